// Round 11
// baseline (115.187 us; speedup 1.0000x reference)
//
#include <hip/hip_runtime.h>
#include <hip/hip_bf16.h>

using bf16x8 = __attribute__((ext_vector_type(8))) short;
using f32x4  = __attribute__((ext_vector_type(4))) float;
using f32x16 = __attribute__((ext_vector_type(16))) float;

constexpr int CH  = 64;
constexpr int HW  = 11;
constexpr int NP  = 121;
constexpr int PPW = 14;            // padded pos-grid row width
constexpr int NROW = 182;          // padded rows (13*14)
constexpr int ICL = 72;            // ic stride (ush) in img/LDS (bank-safe)
constexpr int IMG_USH = NROW * ICL;        // 13104 ush live
constexpr int IMG_I4  = IMG_USH / 8;       // 1638 int4
constexpr int IMG_P   = 13312;             // padded stride: 26 x 1024B segments
constexpr int NSEG    = 26;
constexpr int NO2 = 8192;          // padded o rows (128 oc * 64 ic) for 4 M-tiles
constexpr float EPS = 1e-5f;

// ---- prep: bake BN-scaled gw into gen-MFMA A-fragment order + beta ----
__global__ __launch_bounds__(256) void prep_kernel(
    const float* __restrict__ gw, const float* __restrict__ gb,
    const float* __restrict__ bng, const float* __restrict__ bnb,
    const float* __restrict__ bnm, const float* __restrict__ bnv,
    unsigned short* __restrict__ Aprep, float* __restrict__ Beta)
{
    int o = blockIdx.x * 256 + threadIdx.x;   // padded o = oc*64+ic, oc<128
    if (o >= NO2) return;
    float inv = 0.f, beta = 0.f;
    if (o < 6400) {
        inv  = bng[o] * rsqrtf(bnv[o] + EPS);
        beta = (gb[o] - bnm[o]) * inv + bnb[o];
    }
    Beta[o] = beta;
    int tile = o >> 4, lrow = o & 15;
    #pragma unroll
    for (int jg = 0; jg < 4; ++jg) {
        bf16x8 f;
        #pragma unroll
        for (int r = 0; r < 8; ++r) {
            int k = jg * 8 + r;
            float v = (o < 6400 && k < 18) ? gw[(size_t)o * 18 + k] * inv : 0.f;
            __hip_bfloat16 h = __float2bfloat16(v);
            f[r] = *(short*)&h;
        }
        ((bf16x8*)Aprep)[tile * 64 + jg * 16 + lrow] = f;
    }
}

// ---- pool: coalesced load -> LDS(72-stride) -> stats + linear img dump ----
__global__ __launch_bounds__(256) void pool_kernel(
    const float* __restrict__ x_in,
    unsigned short* __restrict__ img,   // [1024][IMG_P]
    unsigned short* __restrict__ Bg)    // [1024][512]
{
    __shared__ alignas(16) unsigned short xsT[IMG_USH];  // 26208 B
    __shared__ float xh[2][128];
    __shared__ float xhp[2][2][128];

    const int phys = blockIdx.x;
    const int b = (phys & 7) * 128 + (phys >> 3);   // XCD-chunked
    const int t = threadIdx.x, lane = t & 63, wave = t >> 6;
    const float* xb = x_in + (size_t)b * (CH * NP);
    unsigned short* ib = img + (size_t)b * IMG_P;

    for (int i = t; i < IMG_USH / 2; i += 256) ((unsigned int*)xsT)[i] = 0u;
    __syncthreads();

    {   // coalesced fp32 loads (lane->pos), bf16 scatter (2-way banks max)
        int p = (wave & 1) * 64 + lane, ich = wave >> 1;
        if (p < NP) {
            int pp = (p / HW + 1) * PPW + (p % HW + 1);
            float s = 0.f, m = -INFINITY;
            const float* xc = xb + (ich * 32) * NP + p;
            #pragma unroll 8
            for (int q = 0; q < 32; ++q) {
                float v = xc[q * NP];
                s += v; m = fmaxf(m, v);
                __hip_bfloat16 h = __float2bfloat16(v);
                xsT[pp * ICL + ich * 32 + q] = *(unsigned short*)&h;
            }
            xhp[ich][0][p] = s;
            xhp[ich][1][p] = m;
        }
    }
    __syncthreads();
    if (t < NP) {
        xh[0][t] = (xhp[0][0][t] + xhp[1][0][t]) * (1.f / 64.f);
        xh[1][t] = fmaxf(xhp[0][1][t], xhp[1][1][t]);
    }
    __syncthreads();

    // Bg[tap(16)][k(32)] zero-padded gen-B matrix
    for (int i = t; i < 512; i += 256) {
        int tap = i >> 5, k = i & 31;
        float val = 0.f;
        if (tap < 9 && k < 18) {
            int ci = k / 9, o9 = k - ci * 9, u = o9 / 3, v = o9 - u * 3;
            int kh = tap / 3, kw = tap - kh * 3;
            val = xh[ci][(4 * kh + u) * HW + (4 * kw + v)];
        }
        __hip_bfloat16 h = __float2bfloat16(val);
        Bg[b * 512 + i] = *(unsigned short*)&h;
    }

    // linear dump LDS -> img
    for (int i = t; i < IMG_I4; i += 256)
        ((int4*)ib)[i] = ((const int4*)xsT)[i];
}

// ---- main: block = (sample, 32-oc M-tile); 4 waves; 32x32x16 main MFMA ----
__global__ __launch_bounds__(256, 2) void hsi_main(
    const unsigned short* __restrict__ img,
    const unsigned short* __restrict__ Bg,
    const unsigned short* __restrict__ Aprep,
    const float* __restrict__ Beta,
    float* __restrict__ out)
{
    __shared__ alignas(16) unsigned short xs[IMG_P];           // 26624 B
    __shared__ alignas(16) unsigned short strip[36 * 64 * 8];  // 36864 B
    // total 63488 B -> 2 blocks/CU

    const int phys = blockIdx.x;
    const int L = (phys & 7) * 512 + (phys >> 3);   // XCD bijection (4096%8==0)
    const int b = L >> 2, m = L & 3;                // sample, M-tile (32 ocs)
    const int t = threadIdx.x;
    const int lane = t & 63, wave = t >> 6;
    const int lrow = lane & 15, jg = lane >> 4;     // gen-phase lane coords

    // 1) async stage img -> xs (global_load_lds w=16, wave-uniform dest)
    {
        const unsigned short* ib = img + (size_t)b * IMG_P;
        #pragma unroll
        for (int i = 0; i < 7; ++i) {
            int seg = wave + i * 4;                 // 4 waves x 7 = 28 >= 26
            if (seg < NSEG)
                __builtin_amdgcn_global_load_lds(
                    (const __attribute__((address_space(1))) void*)(ib + seg * 512 + lane * 8),
                    (__attribute__((address_space(3))) void*)(xs + seg * 512),
                    16, 0, 0);
        }
    }

    // 2) gen-B fragment
    const bf16x8 Bgen = *(const bf16x8*)(Bg + b * 512 + lrow * 32 + jg * 8);

    // 3) gen: 32 gen-MFMAs/wave (16x16x32) -> 32x32-A fragment-slot strip
    //    strip slot layout: ks = tap*4+icq (36), lane' = hi*32 | (oc^ (tap&7));
    //    writer lane (tap=lrow, jg) of tile tl holds W[oc=tl>>2][ic=(tl&3)*16+jg*4+q][tap]
    #pragma unroll 4
    for (int it = 0; it < 32; ++it) {
        int tl = wave * 32 + it;          // M-tile-local gen tile (0..127)
        int tG = m * 128 + tl;            // global gen tile (<512)
        bf16x8 A = *(const bf16x8*)(Aprep + ((size_t)tG * 64 + lane) * 8);
        f32x4 acc{};
        acc = __builtin_amdgcn_mfma_f32_16x16x32_bf16(A, Bgen, acc, 0, 0, 0);
        float4 bet = *(const float4*)(Beta + tG * 16 + jg * 4);
        if (lrow < 9) {                   // C col = tap = lrow; rows = 4 ics
            float v0 = fmaxf(acc[0] + bet.x, 0.f);
            float v1 = fmaxf(acc[1] + bet.y, 0.f);
            float v2 = fmaxf(acc[2] + bet.z, 0.f);
            float v3 = fmaxf(acc[3] + bet.w, 0.f);
            __hip_bfloat16 h0 = __float2bfloat16(v0), h1 = __float2bfloat16(v1);
            __hip_bfloat16 h2 = __float2bfloat16(v2), h3 = __float2bfloat16(v3);
            unsigned int lo = (unsigned int)*(unsigned short*)&h0 |
                              ((unsigned int)*(unsigned short*)&h1 << 16);
            unsigned int hi_ = (unsigned int)*(unsigned short*)&h2 |
                               ((unsigned int)*(unsigned short*)&h3 << 16);
            int oc_l = tl >> 2, icb = tl & 3;
            // byte = (ks*64 + lane')*16 + sub8:
            //   ks = lrow*4+icb, lane' = (jg>>1)*32 | (oc_l ^ (lrow&7)), sub8 = (jg&1)*8
            int byteoff = ((lrow * 4 + icb) * 64 + ((jg >> 1) * 32 | (oc_l ^ (lrow & 7)))) * 16
                          + (jg & 1) * 8;
            uint2 pk; pk.x = lo; pk.y = hi_;
            *(uint2*)((char*)strip + byteoff) = pk;
        }
    }

    __syncthreads();   // drains async staging (vmcnt) + gen writes; only barrier

    // 4) main GEMM: wave = N-tile (32 pos); 36 k-steps of 32x32x16
    const int col = lane & 31, hi = lane >> 5;
    int p  = wave * 32 + col;
    int pc = p > 120 ? 120 : p;
    int base = (pc / HW) * PPW + (pc % HW);

    f32x16 acc{};
    #pragma unroll
    for (int ks = 0; ks < 36; ++ks) {
        const int tap = ks >> 2, icq = ks & 3;
        const int off = (tap / 3) * PPW + (tap % 3);
        bf16x8 Af = *(const bf16x8*)&strip[(ks * 64 + (hi * 32 | (col ^ (tap & 7)))) * 8];
        bf16x8 Bf = *(const bf16x8*)&xs[(base + off) * ICL + icq * 16 + hi * 8];
        acc = __builtin_amdgcn_mfma_f32_32x32x16_bf16(Af, Bf, acc, 0, 0, 0);
    }

    // 5) store: C/D 32x32 layout col=lane&31, row=(reg&3)+8*(reg>>2)+4*hi (m74/m101)
    float* ob = out + (size_t)b * 100 * NP;
    if (p < NP) {
        #pragma unroll
        for (int reg = 0; reg < 16; ++reg) {
            int ocl = (reg & 3) + 8 * (reg >> 2) + 4 * hi;
            int oc = m * 32 + ocl;
            if (oc < 100) ob[oc * NP + p] = acc[reg];
        }
    }
}

extern "C" void kernel_launch(void* const* d_in, const int* in_sizes, int n_in,
                              void* d_out, int out_size, void* d_ws, size_t ws_size,
                              hipStream_t stream) {
    const float* x  = (const float*)d_in[0];
    const float* gw = (const float*)d_in[1];
    const float* gb = (const float*)d_in[2];
    const float* bg = (const float*)d_in[3];
    const float* bb = (const float*)d_in[4];
    const float* bm = (const float*)d_in[5];
    const float* bv = (const float*)d_in[6];
    float* out = (float*)d_out;

    // ws: Aprep 524288 | Beta 32768 | Bg 1048576 | img 1024*26624  (~28.9 MiB)
    unsigned short* Aprep = (unsigned short*)d_ws;
    float* Beta = (float*)((char*)d_ws + 524288);
    unsigned short* Bgm = (unsigned short*)((char*)d_ws + 557056);
    unsigned short* img = (unsigned short*)((char*)d_ws + 1605632);

    prep_kernel<<<NO2 / 256, 256, 0, stream>>>(gw, gb, bg, bb, bm, bv, Aprep, Beta);
    pool_kernel<<<1024, 256, 0, stream>>>(x, img, Bgm);
    hsi_main<<<1024 * 4, 256, 0, stream>>>(img, Bgm, Aprep, Beta, out);
}

// Round 12
// 76.670 us; speedup vs baseline: 1.5024x; 1.5024x over previous
//
#include <hip/hip_runtime.h>
#include <hip/hip_bf16.h>

using bf16x8 = __attribute__((ext_vector_type(8))) short;
using f32x4  = __attribute__((ext_vector_type(4))) float;

constexpr int CH  = 64;
constexpr int HW  = 11;
constexpr int NP  = 121;
constexpr int PPW = 14;            // padded pos-grid row width
constexpr int NROW = 182;          // padded rows (13*14)
constexpr int ICL = 72;            // ic stride (ush) in img/LDS (bank-safe)
constexpr int IMG_USH = NROW * ICL;        // 13104 ush live
constexpr int IMG_I4  = IMG_USH / 8;       // 1638 int4
constexpr int IMG_P   = 13312;             // padded stride: 26 x 1024B segments
constexpr int NSEG    = 26;
constexpr int NO  = 7168;          // padded o rows (112 oc * 64 ic)
constexpr float EPS = 1e-5f;

__device__ __forceinline__ f32x4 MFMA(bf16x8 a, bf16x8 b, f32x4 c) {
    return __builtin_amdgcn_mfma_f32_16x16x32_bf16(a, b, c, 0, 0, 0);
}

// ---- prep: bake BN-scaled gw into gen-MFMA A-fragment order + beta ----
__global__ __launch_bounds__(256) void prep_kernel(
    const float* __restrict__ gw, const float* __restrict__ gb,
    const float* __restrict__ bng, const float* __restrict__ bnb,
    const float* __restrict__ bnm, const float* __restrict__ bnv,
    unsigned short* __restrict__ Aprep, float* __restrict__ Beta)
{
    int o = blockIdx.x * 256 + threadIdx.x;
    if (o >= NO) return;
    float inv = 0.f, beta = 0.f;
    if (o < 6400) {
        inv  = bng[o] * rsqrtf(bnv[o] + EPS);
        beta = (gb[o] - bnm[o]) * inv + bnb[o];
    }
    Beta[o] = beta;
    int tile = o >> 4, lrow = o & 15;
    #pragma unroll
    for (int jg = 0; jg < 4; ++jg) {
        bf16x8 f;
        #pragma unroll
        for (int r = 0; r < 8; ++r) {
            int k = jg * 8 + r;
            float v = (o < 6400 && k < 18) ? gw[(size_t)o * 18 + k] * inv : 0.f;
            __hip_bfloat16 h = __float2bfloat16(v);
            f[r] = *(short*)&h;
        }
        ((bf16x8*)Aprep)[tile * 64 + jg * 16 + lrow] = f;
    }
}

// ---- pool: coalesced load -> LDS(72-stride) -> stats + linear img dump ----
__global__ __launch_bounds__(256) void pool_kernel(
    const float* __restrict__ x_in,
    unsigned short* __restrict__ img,   // [1024][IMG_P]
    unsigned short* __restrict__ Bg)    // [1024][512]
{
    __shared__ alignas(16) unsigned short xsT[IMG_USH];  // 26208 B
    __shared__ float xh[2][128];
    __shared__ float xhp[2][2][128];

    const int phys = blockIdx.x;
    const int b = (phys & 7) * 128 + (phys >> 3);   // XCD-chunked
    const int t = threadIdx.x, lane = t & 63, wave = t >> 6;
    const float* xb = x_in + (size_t)b * (CH * NP);
    unsigned short* ib = img + (size_t)b * IMG_P;

    for (int i = t; i < IMG_USH / 2; i += 256) ((unsigned int*)xsT)[i] = 0u;
    __syncthreads();

    {   // coalesced fp32 loads (lane->pos), bf16 scatter (2-way banks max)
        int p = (wave & 1) * 64 + lane, ich = wave >> 1;
        if (p < NP) {
            int pp = (p / HW + 1) * PPW + (p % HW + 1);
            float s = 0.f, m = -INFINITY;
            const float* xc = xb + (ich * 32) * NP + p;
            #pragma unroll 8
            for (int q = 0; q < 32; ++q) {
                float v = xc[q * NP];
                s += v; m = fmaxf(m, v);
                __hip_bfloat16 h = __float2bfloat16(v);
                xsT[pp * ICL + ich * 32 + q] = *(unsigned short*)&h;
            }
            xhp[ich][0][p] = s;
            xhp[ich][1][p] = m;
        }
    }
    __syncthreads();
    if (t < NP) {
        xh[0][t] = (xhp[0][0][t] + xhp[1][0][t]) * (1.f / 64.f);
        xh[1][t] = fmaxf(xhp[0][1][t], xhp[1][1][t]);
    }
    __syncthreads();

    // Bg[tap(16)][k(32)] zero-padded gen-B matrix
    for (int i = t; i < 512; i += 256) {
        int tap = i >> 5, k = i & 31;
        float val = 0.f;
        if (tap < 9 && k < 18) {
            int ci = k / 9, o9 = k - ci * 9, u = o9 / 3, v = o9 - u * 3;
            int kh = tap / 3, kw = tap - kh * 3;
            val = xh[ci][(4 * kh + u) * HW + (4 * kw + v)];
        }
        __hip_bfloat16 h = __float2bfloat16(val);
        Bg[b * 512 + i] = *(unsigned short*)&h;
    }

    // linear dump LDS -> img
    for (int i = t; i < IMG_I4; i += 256)
        ((int4*)ib)[i] = ((const int4*)xsT)[i];
}

// ---- main: 512 thr = (sample, 2x14-oc chunks); async staging; 1 barrier ----
__global__ __launch_bounds__(512, 4) void hsi_main(
    const unsigned short* __restrict__ img,
    const unsigned short* __restrict__ Bg,
    const unsigned short* __restrict__ Aprep,
    const float* __restrict__ Beta,
    float* __restrict__ out)
{
    __shared__ alignas(16) unsigned short xs[IMG_P];             // 26624 B
    __shared__ alignas(16) unsigned short strip[2][18 * 64 * 8]; // 36864 B
    // total 63488 B -> 2 blocks/CU (16 waves, 4/SIMD)

    const int phys = blockIdx.x;
    const int L = (phys & 7) * 512 + (phys >> 3);   // XCD-chunked bijection
    const int b = L >> 2, d = L & 3;                // sample, chunk-pair
    const int t = threadIdx.x;
    const int lane = t & 63, wave = t >> 6;
    const int lrow = lane & 15, jg = lane >> 4;
    const int cl = wave >> 2;                       // strip/chunk select (0/1)
    const int chunk = d * 2 + cl;                   // 14-oc chunk (0..7)

    // 1) async stage img -> xs (global_load_lds w=16, wave-uniform dest)
    {
        const unsigned short* ib = img + (size_t)b * IMG_P;
        #pragma unroll
        for (int i = 0; i < 4; ++i) {
            int seg = wave + i * 8;
            if (seg < NSEG)
                __builtin_amdgcn_global_load_lds(
                    (const __attribute__((address_space(1))) void*)(ib + seg * 512 + lane * 8),
                    (__attribute__((address_space(3))) void*)(xs + seg * 512),
                    16, 0, 0);
        }
    }

    // 2) gen-B fragment
    const bf16x8 Bgen = *(const bf16x8*)(Bg + b * 512 + lrow * 32 + jg * 8);

    // 3) gen: 14 MFMAs/wave in 2 batches of 7 (loads hoisted -> L2 latency x2 not x7)
    unsigned short* sp = strip[cl];
    const int tl0 = (wave & 3) * 14;
    #pragma unroll
    for (int bat = 0; bat < 2; ++bat) {
        bf16x8 Ar[7];
        float4 Br[7];
        #pragma unroll
        for (int j = 0; j < 7; ++j) {
            int tG = chunk * 56 + tl0 + bat * 7 + j;   // global gen tile (<448)
            Ar[j] = *(const bf16x8*)(Aprep + ((size_t)tG * 64 + lane) * 8);
            Br[j] = *(const float4*)(Beta + (size_t)tG * 16 + jg * 4);
        }
        #pragma unroll
        for (int j = 0; j < 7; ++j) {
            int tl = tl0 + bat * 7 + j;                // chunk-local tile (0..55)
            f32x4 acc{};
            acc = MFMA(Ar[j], Bgen, acc);
            if (lrow < 9) {                            // C col = tap = lrow
                float v0 = fmaxf(acc[0] + Br[j].x, 0.f);
                float v1 = fmaxf(acc[1] + Br[j].y, 0.f);
                float v2 = fmaxf(acc[2] + Br[j].z, 0.f);
                float v3 = fmaxf(acc[3] + Br[j].w, 0.f);
                __hip_bfloat162 p01 = __float22bfloat162_rn(make_float2(v0, v1));
                __hip_bfloat162 p23 = __float22bfloat162_rn(make_float2(v2, v3));
                uint2 pk;
                pk.x = *(unsigned int*)&p01;           // low = v0 (x), high = v1 (y)
                pk.y = *(unsigned int*)&p23;
                // value = W[oc_l][ic = icb*16 + jg*4 + q][tap=lrow]
                int oc_l = tl >> 2, icb = tl & 3;
                int h   = icb >> 1;                    // k-half
                int jgr = (icb & 1) * 2 + (jg >> 1);   // reader k-group
                int slot = (jgr * 16 + oc_l) ^ lrow;
                *(uint2*)(sp + ((lrow * 2 + h) * 64 + slot) * 8 + (jg & 1) * 4) = pk;
            }
        }
    }

    __syncthreads();   // drains async staging (vmcnt) + gen writes; only barrier

    // 4) main GEMM: wave = (chunk cl, N-pair wave&3); immediate-offset LDS reads
    int p0 = (wave & 3) * 32 + lrow;
    int p1 = p0 + 16;
    int pc0 = p0 > 120 ? 120 : p0;
    int pc1 = p1 > 120 ? 120 : p1;
    int base0 = (pc0 / HW) * PPW + (pc0 % HW);
    int base1 = (pc1 / HW) * PPW + (pc1 % HW);

    // hoisted byte bases: A = spb + (laneb ^ tap*16) + (tap*2+h)*1024
    //                     B = xbN + off(tap)*144 + h*64   (compile-time imms)
    const char* spb = (const char*)sp;
    const int laneb = lane * 16;                       // ^ (tap*16) per tap, 1 v_xor
    const char* xb0 = (const char*)xs + base0 * (ICL * 2) + jg * 16;
    const char* xb1 = (const char*)xs + base1 * (ICL * 2) + jg * 16;

    f32x4 acc0{}, acc1{};
    #pragma unroll
    for (int tap = 0; tap < 9; ++tap) {
        const int av   = laneb ^ (tap * 16);           // (lane^tap)*16, XOR distributes
        const int boff = ((tap / 3) * PPW + (tap % 3)) * (ICL * 2);
        #pragma unroll
        for (int h = 0; h < 2; ++h) {
            bf16x8 Af = *(const bf16x8*)(spb + (tap * 2 + h) * 1024 + av);
            bf16x8 B0 = *(const bf16x8*)(xb0 + boff + h * 64);
            bf16x8 B1 = *(const bf16x8*)(xb1 + boff + h * 64);
            acc0 = MFMA(Af, B0, acc0);
            acc1 = MFMA(Af, B1, acc1);
        }
    }

    float* ob = out + (size_t)b * 100 * NP;
    #pragma unroll
    for (int ri = 0; ri < 4; ++ri) {
        int row = jg * 4 + ri;            // oc-local; rows 14,15 = next chunk
        int oc = chunk * 14 + row;
        if (row < 14 && oc < 100) {
            if (p0 < NP) ob[oc * NP + p0] = acc0[ri];
            if (p1 < NP) ob[oc * NP + p1] = acc1[ri];
        }
    }
}

extern "C" void kernel_launch(void* const* d_in, const int* in_sizes, int n_in,
                              void* d_out, int out_size, void* d_ws, size_t ws_size,
                              hipStream_t stream) {
    const float* x  = (const float*)d_in[0];
    const float* gw = (const float*)d_in[1];
    const float* gb = (const float*)d_in[2];
    const float* bg = (const float*)d_in[3];
    const float* bb = (const float*)d_in[4];
    const float* bm = (const float*)d_in[5];
    const float* bv = (const float*)d_in[6];
    float* out = (float*)d_out;

    // ws: Aprep 458752 | Beta 28672 | Bg 1048576 | img 1024*26624  (~28.8 MiB)
    unsigned short* Aprep = (unsigned short*)d_ws;
    float* Beta = (float*)((char*)d_ws + 458752);
    unsigned short* Bgm = (unsigned short*)((char*)d_ws + 487424);
    unsigned short* img = (unsigned short*)((char*)d_ws + 1536000);

    prep_kernel<<<NO / 256, 256, 0, stream>>>(gw, gb, bg, bb, bm, bv, Aprep, Beta);
    pool_kernel<<<1024, 256, 0, stream>>>(x, img, Bgm);
    hsi_main<<<1024 * 4, 512, 0, stream>>>(img, Bgm, Aprep, Beta, out);
}

// Round 13
// 67.141 us; speedup vs baseline: 1.7156x; 1.1419x over previous
//
#include <hip/hip_runtime.h>
#include <hip/hip_bf16.h>

using bf16x8 = __attribute__((ext_vector_type(8))) short;
using f32x4  = __attribute__((ext_vector_type(4))) float;

constexpr int CH  = 64;
constexpr int HW  = 11;
constexpr int NP  = 121;
constexpr int PPW = 14;            // padded pos-grid row width
constexpr int NROW = 182;          // padded rows (13*14)
constexpr int ICL = 72;            // ic stride (ush) in img/LDS (bank-safe)
constexpr int IMG_USH = NROW * ICL;        // 13104 ush live
constexpr int IMG_I4  = IMG_USH / 8;       // 1638 int4
constexpr int IMG_P   = 13312;             // padded stride: 26 x 1024B segments
constexpr int NSEG    = 26;
constexpr int NO  = 7168;          // padded o rows (112 oc * 64 ic)
constexpr float EPS = 1e-5f;

__device__ __forceinline__ f32x4 MFMA(bf16x8 a, bf16x8 b, f32x4 c) {
    return __builtin_amdgcn_mfma_f32_16x16x32_bf16(a, b, c, 0, 0, 0);
}

// ---- pool (+fused prep): stats, img dump, Bg, Aprep/Beta ----
__global__ __launch_bounds__(256) void pool_kernel(
    const float* __restrict__ x_in,
    const float* __restrict__ gw, const float* __restrict__ gb,
    const float* __restrict__ bng, const float* __restrict__ bnb,
    const float* __restrict__ bnm, const float* __restrict__ bnv,
    unsigned short* __restrict__ img,   // [1024][IMG_P]
    unsigned short* __restrict__ Bg,    // [1024][512]
    unsigned short* __restrict__ Aprep, float* __restrict__ Beta)
{
    __shared__ alignas(16) unsigned short xsT[IMG_USH];  // 26208 B
    __shared__ float xh[2][128];
    __shared__ float xhp[2][2][128];

    const int phys = blockIdx.x;
    const int b = (phys & 7) * 128 + (phys >> 3);   // XCD-chunked
    const int t = threadIdx.x, lane = t & 63, wave = t >> 6;
    const float* xb = x_in + (size_t)b * (CH * NP);
    unsigned short* ib = img + (size_t)b * IMG_P;

    // fused prep: block handles o-rows [phys*7, phys*7+7), threads 0..27
    if (t < 28) {
        int o = phys * 7 + (t >> 2);
        int jgp = t & 3;
        float inv = 0.f, beta = 0.f;
        if (o < 6400) {
            inv  = bng[o] * rsqrtf(bnv[o] + EPS);
            beta = (gb[o] - bnm[o]) * inv + bnb[o];
        }
        if (jgp == 0) Beta[o] = beta;
        int tile = o >> 4, lr = o & 15;
        bf16x8 f;
        #pragma unroll
        for (int r = 0; r < 8; ++r) {
            int k = jgp * 8 + r;
            float v = (o < 6400 && k < 18) ? gw[(size_t)o * 18 + k] * inv : 0.f;
            __hip_bfloat16 h = __float2bfloat16(v);
            f[r] = *(short*)&h;
        }
        ((bf16x8*)Aprep)[tile * 64 + jgp * 16 + lr] = f;
    }

    for (int i = t; i < IMG_USH / 2; i += 256) ((unsigned int*)xsT)[i] = 0u;
    __syncthreads();

    {   // coalesced fp32 loads (lane->pos), bf16 scatter (2-way banks max)
        int p = (wave & 1) * 64 + lane, ich = wave >> 1;
        if (p < NP) {
            int pp = (p / HW + 1) * PPW + (p % HW + 1);
            float s = 0.f, m = -INFINITY;
            const float* xc = xb + (ich * 32) * NP + p;
            #pragma unroll 8
            for (int q = 0; q < 32; ++q) {
                float v = xc[q * NP];
                s += v; m = fmaxf(m, v);
                __hip_bfloat16 h = __float2bfloat16(v);
                xsT[pp * ICL + ich * 32 + q] = *(unsigned short*)&h;
            }
            xhp[ich][0][p] = s;
            xhp[ich][1][p] = m;
        }
    }
    __syncthreads();
    if (t < NP) {
        xh[0][t] = (xhp[0][0][t] + xhp[1][0][t]) * (1.f / 64.f);
        xh[1][t] = fmaxf(xhp[0][1][t], xhp[1][1][t]);
    }
    __syncthreads();

    // Bg[tap(16)][k(32)] zero-padded gen-B matrix
    for (int i = t; i < 512; i += 256) {
        int tap = i >> 5, k = i & 31;
        float val = 0.f;
        if (tap < 9 && k < 18) {
            int ci = k / 9, o9 = k - ci * 9, u = o9 / 3, v = o9 - u * 3;
            int kh = tap / 3, kw = tap - kh * 3;
            val = xh[ci][(4 * kh + u) * HW + (4 * kw + v)];
        }
        __hip_bfloat16 h = __float2bfloat16(val);
        Bg[b * 512 + i] = *(unsigned short*)&h;
    }

    // linear dump LDS -> img
    for (int i = t; i < IMG_I4; i += 256)
        ((int4*)ib)[i] = ((const int4*)xsT)[i];
}

// ---- main: 512 thr; wave = N-tile, B-frags in regs; loop 2 chunks ----
__global__ __launch_bounds__(512, 4) void hsi_main(
    const unsigned short* __restrict__ img,
    const unsigned short* __restrict__ Bg,
    const unsigned short* __restrict__ Aprep,
    const float* __restrict__ Beta,
    float* __restrict__ out)
{
    __shared__ alignas(16) unsigned short xs[IMG_P];             // 26624 B
    __shared__ alignas(16) unsigned short strip[2][18 * 64 * 8]; // 36864 B
    // total 63488 B -> 2 blocks/CU (16 waves, 4/SIMD)

    const int phys = blockIdx.x;
    const int L = (phys & 7) * 512 + (phys >> 3);   // XCD-chunked bijection
    const int b = L >> 2, d = L & 3;                // sample, chunk-pair
    const int t = threadIdx.x;
    const int lane = t & 63, wave = t >> 6;
    const int lrow = lane & 15, jg = lane >> 4;

    // 1) async stage img -> xs (global_load_lds w=16, wave-uniform dest)
    {
        const unsigned short* ib = img + (size_t)b * IMG_P;
        #pragma unroll
        for (int i = 0; i < 4; ++i) {
            int seg = wave + i * 8;
            if (seg < NSEG)
                __builtin_amdgcn_global_load_lds(
                    (const __attribute__((address_space(1))) void*)(ib + seg * 512 + lane * 8),
                    (__attribute__((address_space(3))) void*)(xs + seg * 512),
                    16, 0, 0);
        }
    }

    // 2) gen-B fragment
    const bf16x8 Bgen = *(const bf16x8*)(Bg + b * 512 + lrow * 32 + jg * 8);

    // 3) gen: waves 0-3 -> strip[0] (chunk d*2), waves 4-7 -> strip[1];
    //    14 MFMAs/wave in 2 batches of 7 (hoisted loads)
    const int cl = wave >> 2;
    const int genchunk = d * 2 + cl;
    unsigned short* sp = strip[cl];
    const int tl0 = (wave & 3) * 14;
    #pragma unroll
    for (int bat = 0; bat < 2; ++bat) {
        bf16x8 Ar[7];
        float4 Br[7];
        #pragma unroll
        for (int j = 0; j < 7; ++j) {
            int tG = genchunk * 56 + tl0 + bat * 7 + j;   // global gen tile (<448)
            Ar[j] = *(const bf16x8*)(Aprep + ((size_t)tG * 64 + lane) * 8);
            Br[j] = *(const float4*)(Beta + (size_t)tG * 16 + jg * 4);
        }
        #pragma unroll
        for (int j = 0; j < 7; ++j) {
            int tl = tl0 + bat * 7 + j;                // chunk-local tile (0..55)
            f32x4 acc{};
            acc = MFMA(Ar[j], Bgen, acc);
            if (lrow < 9) {                            // C col = tap = lrow
                float v0 = fmaxf(acc[0] + Br[j].x, 0.f);
                float v1 = fmaxf(acc[1] + Br[j].y, 0.f);
                float v2 = fmaxf(acc[2] + Br[j].z, 0.f);
                float v3 = fmaxf(acc[3] + Br[j].w, 0.f);
                __hip_bfloat162 p01 = __float22bfloat162_rn(make_float2(v0, v1));
                __hip_bfloat162 p23 = __float22bfloat162_rn(make_float2(v2, v3));
                uint2 pk;
                pk.x = *(unsigned int*)&p01;
                pk.y = *(unsigned int*)&p23;
                int oc_l = tl >> 2, icb = tl & 3;
                int h   = icb >> 1;                    // k-half
                int jgr = (icb & 1) * 2 + (jg >> 1);   // reader k-group
                int slot = (jgr * 16 + oc_l) ^ lrow;
                *(uint2*)(sp + ((lrow * 2 + h) * 64 + slot) * 8 + (jg & 1) * 4) = pk;
            }
        }
    }

    __syncthreads();   // drains async staging (vmcnt) + gen writes; only barrier

    // 4) B-frags: wave owns ONE 16-pos N-tile; 18 reads ONCE into registers
    const int p  = wave * 16 + lrow;
    const int pc = p > 120 ? 120 : p;
    const int base = (pc / HW) * PPW + (pc % HW);
    const char* xbp = (const char*)xs + base * (ICL * 2) + jg * 16;
    bf16x8 Bf[18];
    #pragma unroll
    for (int tap = 0; tap < 9; ++tap) {
        const int boff = ((tap / 3) * PPW + (tap % 3)) * (ICL * 2);
        Bf[tap * 2 + 0] = *(const bf16x8*)(xbp + boff);
        Bf[tap * 2 + 1] = *(const bf16x8*)(xbp + boff + 64);
    }

    // 5) chunk loop: A-frags from strip (conflict-free XOR slots), 18 MFMAs each
    float* ob = out + (size_t)b * 100 * NP;
    const int laneb = lane * 16;
    #pragma unroll
    for (int q = 0; q < 2; ++q) {
        const char* spb = (const char*)strip[q];
        const int chunk = d * 2 + q;
        f32x4 acc{};
        #pragma unroll
        for (int tap = 0; tap < 9; ++tap) {
            const int av = laneb ^ (tap * 16);
            #pragma unroll
            for (int h = 0; h < 2; ++h) {
                bf16x8 Af = *(const bf16x8*)(spb + (tap * 2 + h) * 1024 + av);
                acc = MFMA(Af, Bf[tap * 2 + h], acc);
            }
        }
        #pragma unroll
        for (int ri = 0; ri < 4; ++ri) {
            int row = jg * 4 + ri;            // oc-local; rows 14,15 = next chunk
            int oc = chunk * 14 + row;
            if (row < 14 && oc < 100 && p < NP) ob[oc * NP + p] = acc[ri];
        }
    }
}

extern "C" void kernel_launch(void* const* d_in, const int* in_sizes, int n_in,
                              void* d_out, int out_size, void* d_ws, size_t ws_size,
                              hipStream_t stream) {
    const float* x  = (const float*)d_in[0];
    const float* gw = (const float*)d_in[1];
    const float* gb = (const float*)d_in[2];
    const float* bg = (const float*)d_in[3];
    const float* bb = (const float*)d_in[4];
    const float* bm = (const float*)d_in[5];
    const float* bv = (const float*)d_in[6];
    float* out = (float*)d_out;

    // ws: Aprep 458752 | Beta 28672 | Bg 1048576 | img 1024*26624  (~28.8 MiB)
    unsigned short* Aprep = (unsigned short*)d_ws;
    float* Beta = (float*)((char*)d_ws + 458752);
    unsigned short* Bgm = (unsigned short*)((char*)d_ws + 487424);
    unsigned short* img = (unsigned short*)((char*)d_ws + 1536000);

    pool_kernel<<<1024, 256, 0, stream>>>(x, gw, gb, bg, bb, bm, bv,
                                          img, Bgm, Aprep, Beta);
    hsi_main<<<1024 * 4, 512, 0, stream>>>(img, Bgm, Aprep, Beta, out);
}